// Round 2
// baseline (265.716 us; speedup 1.0000x reference)
//
#include <hip/hip_runtime.h>
#include <hip/hip_bf16.h>

// PinSageConv on MI355X — round 8 (resubmit after infra failure; unchanged).
// qgemm v9: swapped-operand MFMA (mfma(B,A)) -> per-lane 4 consecutive output
// cols -> fp8 packed in-register (2x cvt_pk_fp8) -> direct dword stores.
// Deletes the LDS fp8 epilogue (64 ds_write_b8 @ ~16-way conflict + fence +
// 2nd barrier). B-fragment register pipeline deepened to 2-ahead (mod-3
// rotation) and the first 2 k-steps of B are issued BEFORE __syncthreads so
// they hide under the A-stage barrier wait.
// aggk v2: uint4 gathers (16B/lane, 4 neighbors per wave-instr, 13 iters)
// instead of uint2 (8B/lane, 2/instr, 25 iters) — half the load instructions,
// 2x bytes in flight; reduce over lane groups {c,c+16,c+32,c+48}.
// Workspace: q_fp8[100000][256] @0 (25.6MB) | aggF[20000][256] f32 @25.6MB
//            | QwB bf16 @46,080,000 | WwB bf16 @46,211,072.

#define M_TOTAL 100000
#define N_NODES 20000
#define T_NB    50
#define IN_F    256
#define HID_F   256
#define OUT_F   256
#define KCAT    512

typedef __bf16 bf16x8 __attribute__((ext_vector_type(8)));
typedef float  floatx4 __attribute__((ext_vector_type(4)));
typedef float  v2f     __attribute__((ext_vector_type(2)));

__device__ __forceinline__ unsigned short f2bf(float f) {
    unsigned int u = __float_as_uint(f);
    u += 0x7fffu + ((u >> 16) & 1u);          // RTNE
    return (unsigned short)(u >> 16);
}
__device__ __forceinline__ void gload16(const void* g, void* l) {
    __builtin_amdgcn_global_load_lds(
        (const __attribute__((address_space(1))) unsigned int*)g,
        (__attribute__((address_space(3))) unsigned int*)l, 16, 0, 0);
}
__device__ __forceinline__ bf16x8 cvt_frag(float4 a, float4 b) {
    bf16x8 r;
    r[0] = (__bf16)a.x; r[1] = (__bf16)a.y; r[2] = (__bf16)a.z; r[3] = (__bf16)a.w;
    r[4] = (__bf16)b.x; r[5] = (__bf16)b.y; r[6] = (__bf16)b.z; r[7] = (__bf16)b.w;
    return r;
}

// ---------------------------------------------------------------------------
// Kernel 0: convert Qw (65536 f32) and Ww (131072 f32) to bf16.
// ---------------------------------------------------------------------------
__global__ __launch_bounds__(256)
void wcvt(const float* __restrict__ Qw, const float* __restrict__ Ww,
          unsigned short* __restrict__ QwB, unsigned short* __restrict__ WwB) {
    const int e = (blockIdx.x * 256 + threadIdx.x) * 4;
    float4 v;
    unsigned short* dst;
    if (e < 65536) { v = *(const float4*)(Qw + e);           dst = QwB + e; }
    else           { v = *(const float4*)(Ww + (e - 65536)); dst = WwB + (e - 65536); }
    ushort4 s;
    s.x = f2bf(v.x); s.y = f2bf(v.y); s.z = f2bf(v.z); s.w = f2bf(v.w);
    *(ushort4*)dst = s;
}

// ---------------------------------------------------------------------------
// Kernel 1: q = fp8(relu(h @ Qw.T + Qb)).  M=100000 N=256(full) K=256.
// Block = 64 rows x 256 cols, 4 waves (wave = 64x64). A in LDS (bf16,
// swizzle chunk^=row&7), B-frags direct from global QwB, 2-deep register
// pipeline. SWAPPED operands: acc[nt][mt] = mfma(bv, av) so each lane owns
// output (row = mt*16+fr, cols = wc+nt*16+quad*4 .. +3) -> pack 4 fp8 bytes
// in-register, store dword. One barrier total, no LDS epilogue.
// ---------------------------------------------------------------------------
__global__ __launch_bounds__(256)
void qgemm(const float* __restrict__ h, const unsigned short* __restrict__ QwB,
           const float* __restrict__ Qb, unsigned char* __restrict__ q) {
    __shared__ unsigned short ldsA[64 * 256];   // 32 KB

    const int tid  = threadIdx.x;
    const int row0 = blockIdx.x * 64;
    const int lane = tid & 63;
    const int wv   = tid >> 6;
    const int wc   = wv << 6;              // wave's 64-col (n) slice
    const int quad = lane >> 4;
    const int fr   = lane & 15;

    // --- Stage A: 64 h-rows fp32 -> bf16 -> swizzled LDS (2048 8-elem chunks).
#pragma unroll
    for (int i = 0; i < 8; ++i) {
        const int C = tid + i * 256;
        const int r = C >> 5;
        const int c = C & 31;
        const int gr = min(row0 + r, M_TOTAL - 1);
        const float4 p0 = *(const float4*)(h + (size_t)gr * IN_F + c * 8);
        const float4 p1 = *(const float4*)(h + (size_t)gr * IN_F + c * 8 + 4);
        *(bf16x8*)(ldsA + r * 256 + ((c ^ (r & 7)) * 8)) = cvt_frag(p0, p1);
    }

    // --- B preload (k-steps 0,1) issued BEFORE the barrier: latency hides
    // under the stage drain. B-frag row n = wc + nt*16 + fr, k-chunk kb*4+quad.
    const unsigned short* bp = QwB + (size_t)(wc + fr) * IN_F + quad * 8;
    bf16x8 bvp[3][4];
#pragma unroll
    for (int p = 0; p < 2; ++p)
#pragma unroll
        for (int nt = 0; nt < 4; ++nt)
            bvp[p][nt] = *(const bf16x8*)(bp + nt * 16 * IN_F + p * 32);

    floatx4 acc[4][4];                     // [nt][mt]
#pragma unroll
    for (int i = 0; i < 4; ++i)
#pragma unroll
        for (int j = 0; j < 4; ++j)
            acc[i][j] = (floatx4){0.f, 0.f, 0.f, 0.f};

    __syncthreads();

#pragma unroll
    for (int kb = 0; kb < 8; ++kb) {       // K=256, 32/step — no barriers
        if (kb < 6) {
#pragma unroll
            for (int nt = 0; nt < 4; ++nt)
                bvp[(kb + 2) % 3][nt] = *(const bf16x8*)(bp + nt * 16 * IN_F + (kb + 2) * 32);
        }
        bf16x8 av[4];
#pragma unroll
        for (int mt = 0; mt < 4; ++mt) {
            const int r = mt * 16 + fr;
            const int c = kb * 4 + quad;
            av[mt] = *(const bf16x8*)(ldsA + r * 256 + ((c ^ (r & 7)) * 8));
        }
#pragma unroll
        for (int nt = 0; nt < 4; ++nt)
#pragma unroll
            for (int mt = 0; mt < 4; ++mt)
                acc[nt][mt] = __builtin_amdgcn_mfma_f32_16x16x32_bf16(bvp[kb % 3][nt], av[mt], acc[nt][mt], 0, 0, 0);
    }

    // --- Epilogue: lane owns rows mt*16+fr, cols wc+nt*16+quad*4..+3.
    // bias+relu, pack 4 fp8 bytes in-register, one dword store per fragment.
    const int ncol = wc + quad * 4;
#pragma unroll
    for (int nt = 0; nt < 4; ++nt) {
        const float4 b4 = *(const float4*)(Qb + ncol + nt * 16);
#pragma unroll
        for (int mt = 0; mt < 4; ++mt) {
            const int gr = row0 + mt * 16 + fr;
            float v0 = fmaxf(acc[nt][mt][0] + b4.x, 0.f);
            float v1 = fmaxf(acc[nt][mt][1] + b4.y, 0.f);
            float v2 = fmaxf(acc[nt][mt][2] + b4.z, 0.f);
            float v3 = fmaxf(acc[nt][mt][3] + b4.w, 0.f);
            unsigned int wpk = (unsigned int)__builtin_amdgcn_cvt_pk_fp8_f32(v0, v1, 0, false);
            wpk = (unsigned int)__builtin_amdgcn_cvt_pk_fp8_f32(v2, v3, wpk, true);
            if (gr < M_TOTAL)
                *(unsigned int*)(q + (size_t)gr * HID_F + ncol + nt * 16) = wpk;
        }
    }
}

// ---------------------------------------------------------------------------
// Kernel 2: aggF[n] = sum_t w[n,t]*q[nb[n,t]] / sum_t w[n,t]  (fp32 out).
// One wave/node; 4 neighbors per load instruction (quarter-wave each,
// 16B/lane uint4). 13 iterations (t = 4i + sub, lanes with t>=50 carry w=0).
// ---------------------------------------------------------------------------
__global__ __launch_bounds__(256)
void aggk(const unsigned char* __restrict__ q, const int* __restrict__ nb,
          const float* __restrict__ w, float* __restrict__ aggF) {
    const int node = blockIdx.x * 4 + (threadIdx.x >> 6);
    const int lane = threadIdx.x & 63;

    int   idx_l = 0;
    float w_l   = 0.f;
    if (lane < T_NB) {
        idx_l = nb[(size_t)node * T_NB + lane];
        w_l   = w[(size_t)node * T_NB + lane];
    }
    float sw = w_l;
#pragma unroll
    for (int off = 32; off > 0; off >>= 1)
        sw += __shfl_xor(sw, off, 64);

    const int sub = lane >> 4;       // neighbor slot within group of 4
    const int cg  = lane & 15;       // which 16B column chunk of the row
    float a[16];
#pragma unroll
    for (int j = 0; j < 16; ++j) a[j] = 0.f;

#pragma unroll
    for (int i = 0; i < 13; ++i) {
        const int   t   = 4 * i + sub;              // 0..51; t>=50 has w=0,idx=0
        const int   idx = __shfl(idx_l, t, 64);
        const float wt  = __shfl(w_l, t, 64);
        const uint4 u   = *(const uint4*)(q + (size_t)idx * HID_F + cg * 16);
        v2f p;
        p = __builtin_amdgcn_cvt_pk_f32_fp8(u.x, false); a[0]  += wt * p[0]; a[1]  += wt * p[1];
        p = __builtin_amdgcn_cvt_pk_f32_fp8(u.x, true);  a[2]  += wt * p[0]; a[3]  += wt * p[1];
        p = __builtin_amdgcn_cvt_pk_f32_fp8(u.y, false); a[4]  += wt * p[0]; a[5]  += wt * p[1];
        p = __builtin_amdgcn_cvt_pk_f32_fp8(u.y, true);  a[6]  += wt * p[0]; a[7]  += wt * p[1];
        p = __builtin_amdgcn_cvt_pk_f32_fp8(u.z, false); a[8]  += wt * p[0]; a[9]  += wt * p[1];
        p = __builtin_amdgcn_cvt_pk_f32_fp8(u.z, true);  a[10] += wt * p[0]; a[11] += wt * p[1];
        p = __builtin_amdgcn_cvt_pk_f32_fp8(u.w, false); a[12] += wt * p[0]; a[13] += wt * p[1];
        p = __builtin_amdgcn_cvt_pk_f32_fp8(u.w, true);  a[14] += wt * p[0]; a[15] += wt * p[1];
    }
    // lanes {cg, cg+16, cg+32, cg+48} hold partial sums of the same 16 cols
#pragma unroll
    for (int j = 0; j < 16; ++j) {
        a[j] += __shfl_xor(a[j], 16, 64);
        a[j] += __shfl_xor(a[j], 32, 64);
    }

    if (lane < 16) {
        const float inv = 1.0f / sw;
        float* dst = aggF + (size_t)node * HID_F + cg * 16;
#pragma unroll
        for (int k = 0; k < 4; ++k) {
            float4 o = make_float4(a[4 * k] * inv, a[4 * k + 1] * inv,
                                   a[4 * k + 2] * inv, a[4 * k + 3] * inv);
            *(float4*)(dst + 4 * k) = o;
        }
    }
}

// ---------------------------------------------------------------------------
// Kernel 3: out = relu(concat(h[nodeset], aggF) @ Ww.T + Wb).  M=20000 N=256 K=512.
// 64x128 tile, BK=64, async staging (A gathered fp32, B bf16). Wave = 64x32.
// ---------------------------------------------------------------------------
__global__ __launch_bounds__(256)
void fgemm(const float* __restrict__ h, const int* __restrict__ nodeset,
           const float* __restrict__ aggF, const unsigned short* __restrict__ WwB,
           const float* __restrict__ Wb, float* __restrict__ out) {
    __shared__ char smem[32768];
    float* ldsA = (float*)smem;                              // 64 rows x 16 chunks
    unsigned short* ldsB = (unsigned short*)(smem + 16384);  // 128 rows x 8 chunks

    const int tid  = threadIdx.x;
    const int row0 = blockIdx.x * 64;
    const int n0   = blockIdx.y * 128;
    const int lane = tid & 63;
    const int wv   = tid >> 6;
    const int wc   = wv << 5;
    const int fr   = lane & 15;
    const int fk   = (lane >> 4) << 3;
    const int ca   = fk >> 2;
    const int cbB  = fk >> 3;

    int nsrow[4];
#pragma unroll
    for (int i = 0; i < 4; ++i) {
        const int row = (tid + i * 256) >> 4;
        nsrow[i] = nodeset[min(row0 + row, N_NODES - 1)];
    }

    floatx4 acc[4][2];
#pragma unroll
    for (int i = 0; i < 4; ++i)
#pragma unroll
        for (int j = 0; j < 2; ++j)
            acc[i][j] = (floatx4){0.f, 0.f, 0.f, 0.f};

    for (int kb = 0; kb < 8; ++kb) {
        if (kb) __syncthreads();
#pragma unroll
        for (int i = 0; i < 4; ++i) {
            const int L   = tid + i * 256;
            const int row = L >> 4;
            const int cg  = (L & 15) ^ (row & 15);
            const float* src = (kb < 4)
                ? h    + (size_t)nsrow[i] * IN_F + kb * 64 + cg * 4
                : aggF + (size_t)min(row0 + row, N_NODES - 1) * HID_F + (kb - 4) * 64 + cg * 4;
            gload16(src, smem + L * 16);
        }
#pragma unroll
        for (int i = 0; i < 4; ++i) {
            const int L   = tid + i * 256;
            const int row = L >> 3;
            const int cg  = (L & 7) ^ (row & 7);
            gload16(WwB + (size_t)(n0 + row) * KCAT + kb * 64 + cg * 8, smem + 16384 + L * 16);
        }
        __syncthreads();

#pragma unroll
        for (int ks = 0; ks < 2; ++ks) {
            bf16x8 av[4], bv[2];
#pragma unroll
            for (int mt = 0; mt < 4; ++mt) {
                const int row = mt * 16 + fr;
                const int sw  = row & 15;
                const int c0  = ks * 8 + ca;
                const float4 p0 = *(const float4*)(ldsA + (row * 16 + (c0 ^ sw)) * 4);
                const float4 p1 = *(const float4*)(ldsA + (row * 16 + ((c0 + 1) ^ sw)) * 4);
                av[mt] = cvt_frag(p0, p1);
            }
#pragma unroll
            for (int nt = 0; nt < 2; ++nt) {
                const int row = wc + nt * 16 + fr;
                const int sw  = row & 7;
                bv[nt] = *reinterpret_cast<const bf16x8*>(ldsB + row * 64 + ((ks * 4 + cbB) ^ sw) * 8);
            }
#pragma unroll
            for (int mt = 0; mt < 4; ++mt)
#pragma unroll
                for (int nt = 0; nt < 2; ++nt)
                    acc[mt][nt] = __builtin_amdgcn_mfma_f32_16x16x32_bf16(av[mt], bv[nt], acc[mt][nt], 0, 0, 0);
        }
    }

    const int erow = (lane >> 4) << 2;
    const int ecol = lane & 15;
#pragma unroll
    for (int nt = 0; nt < 2; ++nt) {
        const int gcol = n0 + wc + nt * 16 + ecol;
        const float bias = Wb[gcol];
#pragma unroll
        for (int mt = 0; mt < 4; ++mt)
#pragma unroll
            for (int r = 0; r < 4; ++r) {
                const int gr = row0 + mt * 16 + erow + r;
                if (gr < N_NODES) {
                    const float v = acc[mt][nt][r] + bias;
                    out[(size_t)gr * OUT_F + gcol] = (v > 0.f ? v : 0.f);
                }
            }
    }
}

// ---------------------------------------------------------------------------
// Kernel 4: in-place row L2 normalize. One wave per row.
// ---------------------------------------------------------------------------
__global__ __launch_bounds__(256)
void normk(float* __restrict__ out) {
    const int row = blockIdx.x * 4 + (threadIdx.x >> 6);
    const int lane = threadIdx.x & 63;
    float4 v = *(float4*)(out + (size_t)row * OUT_F + lane * 4);
    float ss = v.x * v.x + v.y * v.y + v.z * v.z + v.w * v.w;
#pragma unroll
    for (int off = 32; off > 0; off >>= 1)
        ss += __shfl_xor(ss, off, 64);
    const float s = rsqrtf(ss);
    v.x *= s; v.y *= s; v.z *= s; v.w *= s;
    *(float4*)(out + (size_t)row * OUT_F + lane * 4) = v;
}

extern "C" void kernel_launch(void* const* d_in, const int* in_sizes, int n_in,
                              void* d_out, int out_size, void* d_ws, size_t ws_size,
                              hipStream_t stream) {
    const float* h        = (const float*)d_in[0];
    const int*   nodeset  = (const int*)d_in[1];
    const int*   nb_nodes = (const int*)d_in[2];
    const float* nb_w     = (const float*)d_in[3];
    const float* Qw       = (const float*)d_in[4];
    const float* Qb       = (const float*)d_in[5];
    const float* Ww       = (const float*)d_in[6];
    const float* Wb       = (const float*)d_in[7];
    float* out = (float*)d_out;

    unsigned char*  q    = (unsigned char*)d_ws;                          // 25.6 MB
    float*          aggF = (float*)((char*)d_ws + 25600000);              // 20.48 MB
    unsigned short* QwB  = (unsigned short*)((char*)d_ws + 46080000);     // 128 KB
    unsigned short* WwB  = (unsigned short*)((char*)d_ws + 46211072);     // 256 KB

    wcvt <<<dim3(192),                    256, 0, stream>>>(Qw, Ww, QwB, WwB);
    qgemm<<<dim3((M_TOTAL + 63) / 64),    256, 0, stream>>>(h, QwB, Qb, q);
    aggk <<<dim3(N_NODES / 4),            256, 0, stream>>>(q, nb_nodes, nb_w, aggF);
    fgemm<<<dim3((N_NODES + 63) / 64, 2), 256, 0, stream>>>(h, nodeset, aggF, WwB, Wb, out);
    normk<<<dim3(N_NODES / 4),            256, 0, stream>>>(out);
}